// Round 14
// baseline (415.849 us; speedup 1.0000x reference)
//
#include <hip/hip_runtime.h>

typedef unsigned short u16;
typedef unsigned int u32;
typedef __attribute__((ext_vector_type(4))) float f32x4;
typedef __attribute__((ext_vector_type(16))) float f32x16;
typedef __attribute__((ext_vector_type(8))) short bf16x8;   // 8 bf16 (4 VGPRs)
typedef __attribute__((ext_vector_type(4))) float float4v;
typedef __attribute__((ext_vector_type(4))) unsigned short u16x4;
typedef __attribute__((ext_vector_type(8))) unsigned short u16x8;

__device__ __forceinline__ float bf2f(u16 u) { return __uint_as_float(((u32)u) << 16); }
__device__ __forceinline__ u16 f2bf(float f) {
  u32 x = __float_as_uint(f);
  x += 0x7fffu + ((x >> 16) & 1u);   // RNE; values here are finite
  return (u16)(x >> 16);
}
__device__ __forceinline__ u32 cvtpk(float lo, float hi_) {  // [lo | hi] bf16 pair
  u32 r;
  asm("v_cvt_pk_bf16_f32 %0, %1, %2" : "=v"(r) : "v"(lo), "v"(hi_));
  return r;
}

__device__ __forceinline__ void gll16(const void* g, void* l) {
  __builtin_amdgcn_global_load_lds((const __attribute__((address_space(1))) void*)g,
                                   (__attribute__((address_space(3))) void*)l, 16, 0, 0);
}

#define MFMA_BF16(a, b, c) __builtin_amdgcn_mfma_f32_16x16x32_bf16((a), (b), (c), 0, 0, 0)
#define MFMA32(a, b, c) __builtin_amdgcn_mfma_f32_32x32x16_bf16((a), (b), (c), 0, 0, 0)

#define BARRIER() __builtin_amdgcn_s_barrier()
#define SETP(n) __builtin_amdgcn_s_setprio(n)
#define VMCNT(n) asm volatile("s_waitcnt vmcnt(" #n ")" ::: "memory")

// ------------------------------- prep: all casts + rope tables, one launch ----------------
__global__ __launch_bounds__(256) void prep_kernel(const float* __restrict__ x,
                                                   const float* __restrict__ w_qkv,
                                                   const float* __restrict__ w_out,
                                                   u16* __restrict__ xb,
                                                   u16* __restrict__ wqkvb,
                                                   u16* __restrict__ woutb,
                                                   float2* __restrict__ cst) {
  const int tid0 = blockIdx.x * 256 + threadIdx.x;
  const int stride = gridDim.x * 256;
#pragma unroll 1
  for (int i = tid0 * 4; i < 16777216; i += stride * 4) {
    const float4v v = *(const float4v*)(x + i);
    u16x4 o; o[0] = f2bf(v[0]); o[1] = f2bf(v[1]); o[2] = f2bf(v[2]); o[3] = f2bf(v[3]);
    *(u16x4*)(xb + i) = o;
  }
#pragma unroll 1
  for (int i = tid0 * 4; i < 12582912; i += stride * 4) {
    const float4v v = *(const float4v*)(w_qkv + i);
    u16x4 o; o[0] = f2bf(v[0]); o[1] = f2bf(v[1]); o[2] = f2bf(v[2]); o[3] = f2bf(v[3]);
    *(u16x4*)(wqkvb + i) = o;
  }
#pragma unroll 1
  for (int i = tid0 * 4; i < 4194304; i += stride * 4) {
    const float4v v = *(const float4v*)(w_out + i);
    u16x4 o; o[0] = f2bf(v[0]); o[1] = f2bf(v[1]); o[2] = f2bf(v[2]); o[3] = f2bf(v[3]);
    *(u16x4*)(woutb + i) = o;
  }
#pragma unroll 1
  for (int idx = tid0; idx < 131072; idx += stride) {
    const int t = idx >> 6, j = idx & 63;
    const float inv = powf(10000.0f, -(float)(j & 31) * (1.0f / 32.0f));
    const float ang = (float)t * inv;
    cst[idx] = make_float2(cosf(ang), sinf(ang));
  }
}

// ------------------------------- GEMM 256x256 4-phase dual-B (fastest measured) ------------
#define PH_MFMA(MG, NG, BF)                                                      \
  do {                                                                           \
    _Pragma("unroll") for (int i_ = 0; i_ < 4; ++i_)                             \
      _Pragma("unroll") for (int jn_ = 0; jn_ < 2; ++jn_)                        \
        _Pragma("unroll") for (int ks_ = 0; ks_ < 2; ++ks_)                      \
          acc[(MG) * 4 + i_][(NG) * 2 + jn_] =                                   \
              MFMA_BF16(af[i_][ks_], BF[jn_][ks_],                               \
                        acc[(MG) * 4 + i_][(NG) * 2 + jn_]);                     \
  } while (0)

#define LDB_M(bb, ng, BF)                                                        \
  do {                                                                           \
    const char* base_ = (const char*)&LDS[bb][1][ng][0];                         \
    _Pragma("unroll") for (int jn_ = 0; jn_ < 2; ++jn_) {                        \
      const int R_ = jn_ * 64 + wc * 16 + l15;                                   \
      _Pragma("unroll") for (int ks_ = 0; ks_ < 2; ++ks_)                        \
        BF[jn_][ks_] = *(const bf16x8*)(base_ + R_ * 128 +                       \
                                        ((ks_ * 64 + l4 * 16) ^ ((R_ & 7) << 4)));\
    }                                                                            \
  } while (0)

template <int MODE>
__global__ __launch_bounds__(512, 2) void gemm_bt8(const u16* __restrict__ A,
                                                   const u16* __restrict__ B,
                                                   void* __restrict__ Cv, int M, int N, int K,
                                                   int lda, int ldb, int ldc,
                                                   const float2* __restrict__ cst) {
  __shared__ __align__(16) u16 LDS[2][2][2][128 * 64];  // [buf][A=0/B=1][half][128x64]
  const int nbn = N >> 8;
  const int nwg = gridDim.x;                       // divisible by 8 for our shapes
  const int wg = (blockIdx.x & 7) * (nwg >> 3) + (blockIdx.x >> 3);  // XCD swizzle (T1)
  const int bm = wg / nbn, bn = wg % nbn;
  const int tid = threadIdx.x;
  const int w = tid >> 6, l = tid & 63, l15 = l & 15, l4 = l >> 4;
  const int wr = w >> 2, wc = w & 3;               // 2 M-warps x 4 N-warps
  const u16* Abase = A + (size_t)bm * 256 * lda;
  const u16* Bbase = B + (size_t)bn * 256 * ldb;
  const int NT = K >> 6;

  f32x4 acc[8][4] = {};
  bf16x8 af[4][2], bfr0[2][2], bfr1[2][2];

  auto STAGE = [&](int sel, int h, int t) {
    const u16* src = (sel ? Bbase + (size_t)h * 128 * ldb : Abase + (size_t)h * 128 * lda) +
                     t * 64;
    const int ld = sel ? ldb : lda;
    char* dst = (char*)&LDS[t & 1][sel][h][0];
#pragma unroll
    for (int j = 0; j < 2; ++j) {
      const int o = j * 8192 + tid * 16;
      const int r = o >> 7;
      const int cb = (o & 127) ^ ((r & 7) << 4);
      gll16(src + (size_t)r * ld + (cb >> 1), dst + o);
    }
  };
  auto LDA_ = [&](int bb, int mg) {
    const char* base = (const char*)&LDS[bb][0][mg][0];
#pragma unroll
    for (int i = 0; i < 4; ++i) {
      const int R = i * 32 + wr * 16 + l15;
#pragma unroll
      for (int ks = 0; ks < 2; ++ks)
        af[i][ks] = *(const bf16x8*)(base + R * 128 + ((ks * 64 + l4 * 16) ^ ((R & 7) << 4)));
    }
  };

  // prologue: tile0 {A0,B0,A1,B1} + tile1 {B0,B1,A1}; vmcnt(6) completes tile0
  STAGE(0, 0, 0); STAGE(1, 0, 0); STAGE(0, 1, 0); STAGE(1, 1, 0);
  if (NT > 1) { STAGE(1, 0, 1); STAGE(1, 1, 1); STAGE(0, 1, 1); }
  VMCNT(6);
  BARRIER();

  for (int T = 0; T < NT; ++T) {
    const int bb = T & 1;
    LDA_(bb, 0); LDB_M(bb, 0, bfr0);
    if (T + 1 < NT) STAGE(0, 0, T + 1);
    BARRIER();
    SETP(1); PH_MFMA(0, 0, bfr0); SETP(0);
    BARRIER();
    LDB_M(bb, 1, bfr1);
    if (T + 2 < NT) STAGE(1, 0, T + 2);
    BARRIER();
    SETP(1); PH_MFMA(0, 1, bfr1); SETP(0);
    BARRIER();
    LDA_(bb, 1);
    if (T + 2 < NT) STAGE(1, 1, T + 2);
    BARRIER();
    SETP(1); PH_MFMA(1, 1, bfr1); SETP(0);
    BARRIER();
    if (T + 2 < NT) STAGE(0, 1, T + 2);
    BARRIER();
    SETP(1); PH_MFMA(1, 0, bfr0); SETP(0);
    if (T + 2 < NT) { VMCNT(6); } else { VMCNT(0); }
    BARRIER();
  }

  // epilogue: C/D layout col = lane&15, row = (lane>>4)*4 + reg (m89-verified)
#pragma unroll
  for (int mf = 0; mf < 8; ++mf) {
    const int mg = mf >> 2, i = mf & 3;
    const int row0 = bm * 256 + mg * 128 + i * 32 + wr * 16 + l4 * 4;
#pragma unroll
    for (int f = 0; f < 4; ++f) {
      const int col = bn * 256 + f * 64 + wc * 16 + l15;
      const f32x4 a = acc[mf][f];
      if (MODE == 0) {
        float* C = (float*)Cv;
#pragma unroll
        for (int r = 0; r < 4; ++r)
          C[(size_t)(row0 + r) * ldc + col] = a[r];
      } else if (bn < 16) {  // q,k region: RoPE in fp32, bf16 store to split-half cols
        u16* C = (u16*)Cv;
        const int hc = (f * 64 + wc * 16 + l15) & 127;  // head-relative col
        const int jj = hc >> 1;
        const int odd = hc & 1;
        const int co = (col & ~127) + jj + (odd << 6);  // output col
#pragma unroll
        for (int r = 0; r < 4; ++r) {
          const int row = row0 + r;
          const int seq = row & 2047;
          const float v = a[r];
          const float p = __shfl_xor(v, 1);             // partner in (2j,2j+1) pair
          const float2 cv = cst[seq * 64 + jj];
          const float res = odd ? (p * cv.y + v * cv.x)  // out[64+j] = x1*s + x2*c
                                : (v * cv.x - p * cv.y); // out[j]    = x1*c - x2*s
          C[(size_t)row * 6144 + co] = f2bf(res);
        }
      } else {               // V region: transposed into qkvb v-cols, u16x4 (4 consec s)
        u16* C = (u16*)Cv;
        const int batch = row0 >> 11;
        const int s0 = row0 & 2047;
        const int vcol = col - 4096;
        u16* vb = C + (size_t)((batch * 16 + (vcol >> 7)) * 128 + (vcol & 127)) * 6144 +
                  4096 + s0;
        union { u32 u[2]; u16x4 v; } pk;
        pk.u[0] = cvtpk(a[0], a[1]);
        pk.u[1] = cvtpk(a[2], a[3]);
        *(u16x4*)vb = pk.v;
      }
    }
  }
}

// ------------------------------- flash attention (8-wave, 32x32, swapped-QK^T) ---------------
// grid(x=bh=64, y=4): each block handles TWO complementary q-supertiles (qt = y+4, then 3-y)
// -> per-block work = 36 tile-units, constant; 256 blocks = one balanced wave (1 block/CU).
// Triple-buffered K/V staging (counted vmcnt(4)); defer-max (T13, THR=8).
__global__ __launch_bounds__(512, 2) void flash_attn(u16* __restrict__ qkvb) {
  __shared__ __align__(16) char smem[98304];  // K 3buf [3][16KB] | V 3buf [3][16KB]
  const int bh = blockIdx.x;
  const int b = bh >> 4, h = bh & 15;
  const int tid = threadIdx.x;
  const int w = tid >> 6, l = tid & 63;
  const int l31 = l & 31, hi = l >> 5;

  const u16* Kg0 = qkvb + (size_t)b * 2048 * 6144 + 2048 + h * 128;        // + key*6144
  const u16* Vg0 = qkvb + (size_t)bh * 128 * 6144 + 4096;                  // + d*6144 + key

  auto STAGE = [&](int t, int bi) {
    const u16* Kg = Kg0 + (size_t)t * 64 * 6144;
    const u16* Vg = Vg0 + t * 64;
    char* kd = smem + bi * 16384;
    char* vd = smem + 49152 + bi * 16384;
#pragma unroll
    for (int j = 0; j < 2; ++j) {
      const int o = j * 8192 + tid * 16;
      {  // K tile [64][128] u16, 256B rows, 4-bit swizzle
        const int r = o >> 8;
        const int cb = (o & 255) ^ ((r & 15) << 4);
        gll16(Kg + (size_t)r * 6144 + (cb >> 1), kd + o);
      }
      {  // V^T tile [128][64] u16, 128B rows, 3-bit swizzle; global row stride 6144
        const int r = o >> 7;
        const int cb = (o & 127) ^ ((r & 7) << 4);
        gll16(Vg + (size_t)r * 6144 + (cb >> 1), vd + o);
      }
    }
  };

#pragma unroll 1
  for (int pass = 0; pass < 2; ++pass) {
    const int qt = pass == 0 ? (int)blockIdx.y + 4 : 3 - (int)blockIdx.y;
    const int q0 = qt * 256 + w * 32;           // wave's first q row
    const int qg = q0 + l31;                    // this lane's q (S^T column)

    bf16x8 qf[8];
    {
      const u16* Qrow = qkvb + (size_t)(b * 2048 + qg) * 6144 + h * 128 + hi * 8;
#pragma unroll
      for (int d = 0; d < 8; ++d) qf[d] = *(const bf16x8*)(Qrow + d * 16);
    }

    f32x16 ot[4];
#pragma unroll
    for (int dt = 0; dt < 4; ++dt) ot[dt] = 0.f;
    float mrun = -1e30f, lrun = 0.f;

    const int NT = 4 * qt + 4;

    // prologue: tiles 0,1 into bufs 0,1; vmcnt(4) completes tile 0 (tile 1 in flight)
    STAGE(0, 0);
    STAGE(1, 1);                               // NT >= 4 always
    VMCNT(4);
    BARRIER();

    int cur = 0;
#pragma unroll 1
    for (int kt = 0; kt < NT; ++kt) {
      const int nxt = (cur == 0) ? 2 : cur - 1;     // (kt+2) % 3
      if (kt + 2 < NT) STAGE(kt + 2, nxt);

      if (kt * 64 <= q0 + 31) {  // wave-uniform: tile has unmasked keys for this wave
        const char* Kb = smem + cur * 16384;
        const char* Vb = smem + 49152 + cur * 16384;

        // ---- S^T[key][q] = K x Q^T ----
        f32x16 sa[2];
        sa[0] = 0.f; sa[1] = 0.f;
#pragma unroll
        for (int ks2 = 0; ks2 < 2; ++ks2) {
          const int R = ks2 * 32 + l31;
#pragma unroll
          for (int d = 0; d < 8; ++d) {
            const bf16x8 kf = *(const bf16x8*)(Kb + R * 256 +
                                               ((d * 32 + hi * 16) ^ ((R & 15) << 4)));
            sa[ks2] = MFMA32(kf, qf[d], sa[ks2]);
          }
        }

        // ---- scale + mask + tile max ----
        const float SCALE = 0.08838834764831845f;
        float tmax = -1e30f;
        if (kt * 64 + 63 > q0) {
#pragma unroll
          for (int ks2 = 0; ks2 < 2; ++ks2)
#pragma unroll
            for (int rg = 0; rg < 16; ++rg) {
              const int key = kt * 64 + ks2 * 32 + (rg & 3) + 8 * (rg >> 2) + 4 * hi;
              float sv = sa[ks2][rg] * SCALE;
              sv = (key > qg) ? -1e30f : sv;
              sa[ks2][rg] = sv;
              tmax = fmaxf(tmax, sv);
            }
        } else {
#pragma unroll
          for (int ks2 = 0; ks2 < 2; ++ks2)
#pragma unroll
            for (int rg = 0; rg < 16; ++rg) {
              const float sv = sa[ks2][rg] * SCALE;
              sa[ks2][rg] = sv;
              tmax = fmaxf(tmax, sv);
            }
        }
        tmax = fmaxf(tmax, __shfl_xor(tmax, 32));

        // ---- online softmax with defer-max (T13, THR=8): P bounded by e^8 ----
        if (!__all(tmax - mrun <= 8.0f)) {
          const float mnew = fmaxf(mrun, tmax);
          const float alpha = __expf(mrun - mnew);
          mrun = mnew;
          lrun *= alpha;
#pragma unroll
          for (int dt = 0; dt < 4; ++dt)
#pragma unroll
            for (int rg = 0; rg < 16; ++rg) ot[dt][rg] *= alpha;
        }
        float rsum = 0.f;
#pragma unroll
        for (int ks2 = 0; ks2 < 2; ++ks2)
#pragma unroll
          for (int rg = 0; rg < 16; ++rg) {
            const float pv = __expf(sa[ks2][rg] - mrun);
            sa[ks2][rg] = pv;
            rsum += pv;
          }
        rsum += __shfl_xor(rsum, 32);
        lrun += rsum;

        // ---- P^T B-fragments: pack bf16 + lane^32 exchange of 4-key quads ----
        bf16x8 pfrag[4];
#pragma unroll
        for (int t = 0; t < 4; ++t) {
          const int ks2 = t >> 1;
          const int gA = 2 * (t & 1);
          const int gB = gA + 1;
          const u32 a0 = cvtpk(sa[ks2][gA * 4 + 0], sa[ks2][gA * 4 + 1]);
          const u32 a1 = cvtpk(sa[ks2][gA * 4 + 2], sa[ks2][gA * 4 + 3]);
          const u32 b0 = cvtpk(sa[ks2][gB * 4 + 0], sa[ks2][gB * 4 + 1]);
          const u32 b1 = cvtpk(sa[ks2][gB * 4 + 2], sa[ks2][gB * 4 + 3]);
          const u32 snd0 = hi ? a0 : b0;
          const u32 snd1 = hi ? a1 : b1;
          const u32 rcv0 = (u32)__shfl_xor((int)snd0, 32);
          const u32 rcv1 = (u32)__shfl_xor((int)snd1, 32);
          union { u32 u[4]; bf16x8 v; } pk;
          pk.u[0] = hi ? rcv0 : a0;
          pk.u[1] = hi ? rcv1 : a1;
          pk.u[2] = hi ? b0 : rcv0;
          pk.u[3] = hi ? b1 : rcv1;
          pfrag[t] = pk.v;
        }

        // ---- O^T[d][q] += V^T x P^T ----
#pragma unroll
        for (int dt = 0; dt < 4; ++dt) {
          const int R = dt * 32 + l31;
#pragma unroll
          for (int t = 0; t < 4; ++t) {
            const bf16x8 vf = *(const bf16x8*)(Vb + R * 128 +
                                               ((t * 32 + hi * 16) ^ ((R & 7) << 4)));
            ot[dt] = MFMA32(vf, pfrag[t], ot[dt]);
          }
        }
      }

      // counted wait: tile kt+1 complete; tile kt+2's 4 loads stay in flight
      if (kt + 2 < NT) { VMCNT(4); } else { VMCNT(0); }
      BARRIER();
      cur = (cur == 2) ? 0 : cur + 1;
    }

    // ---- epilogue: O^T -> LDS (per-wave 8KB, swizzled) -> coalesced global y ----
    const float inv = 1.0f / lrun;
    char* E = smem + w * 8192;  // [32 q][128 d] u16, 256B rows, 4-bit swizzle (wave-private)
#pragma unroll
    for (int dt = 0; dt < 4; ++dt)
#pragma unroll
      for (int rp = 0; rp < 8; ++rp) {
        const int rg = 2 * rp;
        const int d0 = dt * 32 + (rg & 3) + 8 * (rg >> 2) + 4 * hi;
        const u32 pkv = cvtpk(ot[dt][rg] * inv, ot[dt][rg + 1] * inv);
        *(u32*)(E + l31 * 256 + ((d0 * 2) ^ ((l31 & 15) << 4))) = pkv;
      }
#pragma unroll
    for (int p = 0; p < 8; ++p) {
      const int q = p * 4 + (l >> 4);
      const int c = l & 15;
      const bf16x8 vv = *(const bf16x8*)(E + q * 256 + ((c * 16) ^ ((q & 15) << 4)));
      *(bf16x8*)(qkvb + (size_t)(b * 2048 + q0 + q) * 6144 + h * 128 + c * 8) = vv;
    }

    BARRIER();  // protect E region (overlaps K/V bufs) before next pass's staging
  }
}

// ------------------------------- launch -------------------------------
extern "C" void kernel_launch(void* const* d_in, const int* in_sizes, int n_in,
                              void* d_out, int out_size, void* d_ws, size_t ws_size,
                              hipStream_t stream) {
  const float* x     = (const float*)d_in[0];
  // d_in[1] = mask (causal, implemented analytically)
  const float* w_qkv = (const float*)d_in[2];
  const float* w_out = (const float*)d_in[3];
  float* out = (float*)d_out;
  char* ws = (char*)d_ws;

  // Peak workspace: 161 MB
  u16* woutb = (u16*)(ws);                          // [0,8) MB, live till GEMM2
  u16* xb    = (u16*)(ws + ((size_t)8 << 20));      // [8,40)
  u16* wqkvb = (u16*)(ws + ((size_t)40 << 20));     // [40,64)
  u16* qkvb  = (u16*)(ws + ((size_t)64 << 20));     // [64,160); V transposed in v-cols
  float2* cst = (float2*)(ws + ((size_t)160 << 20)); // 1 MB packed cos/sin

  prep_kernel<<<2048, 256, 0, stream>>>(x, w_qkv, w_out, xb, wqkvb, woutb, cst);
  gemm_bt8<1><<<768, 512, 0, stream>>>(xb, wqkvb, qkvb, 8192, 6144, 2048,
                                       2048, 2048, 6144, cst);
  flash_attn<<<dim3(64, 4), 512, 0, stream>>>(qkvb);
  gemm_bt8<0><<<256, 512, 0, stream>>>(qkvb, woutb, out, 8192, 2048, 2048,
                                       6144, 2048, 2048, nullptr);
}

// Round 15
// 402.070 us; speedup vs baseline: 1.0343x; 1.0343x over previous
//
#include <hip/hip_runtime.h>

typedef unsigned short u16;
typedef unsigned int u32;
typedef __attribute__((ext_vector_type(4))) float f32x4;
typedef __attribute__((ext_vector_type(16))) float f32x16;
typedef __attribute__((ext_vector_type(8))) short bf16x8;   // 8 bf16 (4 VGPRs)
typedef __attribute__((ext_vector_type(4))) float float4v;
typedef __attribute__((ext_vector_type(4))) unsigned short u16x4;
typedef __attribute__((ext_vector_type(8))) unsigned short u16x8;

__device__ __forceinline__ float bf2f(u16 u) { return __uint_as_float(((u32)u) << 16); }
__device__ __forceinline__ u16 f2bf(float f) {
  u32 x = __float_as_uint(f);
  x += 0x7fffu + ((x >> 16) & 1u);   // RNE; values here are finite
  return (u16)(x >> 16);
}
__device__ __forceinline__ u32 cvtpk(float lo, float hi_) {  // [lo | hi] bf16 pair
  u32 r;
  asm("v_cvt_pk_bf16_f32 %0, %1, %2" : "=v"(r) : "v"(lo), "v"(hi_));
  return r;
}

__device__ __forceinline__ void gll16(const void* g, void* l) {
  __builtin_amdgcn_global_load_lds((const __attribute__((address_space(1))) void*)g,
                                   (__attribute__((address_space(3))) void*)l, 16, 0, 0);
}

#define MFMA_BF16(a, b, c) __builtin_amdgcn_mfma_f32_16x16x32_bf16((a), (b), (c), 0, 0, 0)
#define MFMA32(a, b, c) __builtin_amdgcn_mfma_f32_32x32x16_bf16((a), (b), (c), 0, 0, 0)

#define BARRIER() __builtin_amdgcn_s_barrier()
#define SETP(n) __builtin_amdgcn_s_setprio(n)
#define VMCNT(n) asm volatile("s_waitcnt vmcnt(" #n ")" ::: "memory")

// ------------------------------- prep: all casts + rope tables, one launch ----------------
__global__ __launch_bounds__(256) void prep_kernel(const float* __restrict__ x,
                                                   const float* __restrict__ w_qkv,
                                                   const float* __restrict__ w_out,
                                                   u16* __restrict__ xb,
                                                   u16* __restrict__ wqkvb,
                                                   u16* __restrict__ woutb,
                                                   float2* __restrict__ cst) {
  const int tid0 = blockIdx.x * 256 + threadIdx.x;
  const int stride = gridDim.x * 256;
#pragma unroll 1
  for (int i = tid0 * 4; i < 16777216; i += stride * 4) {
    const float4v v = *(const float4v*)(x + i);
    u16x4 o; o[0] = f2bf(v[0]); o[1] = f2bf(v[1]); o[2] = f2bf(v[2]); o[3] = f2bf(v[3]);
    *(u16x4*)(xb + i) = o;
  }
#pragma unroll 1
  for (int i = tid0 * 4; i < 12582912; i += stride * 4) {
    const float4v v = *(const float4v*)(w_qkv + i);
    u16x4 o; o[0] = f2bf(v[0]); o[1] = f2bf(v[1]); o[2] = f2bf(v[2]); o[3] = f2bf(v[3]);
    *(u16x4*)(wqkvb + i) = o;
  }
#pragma unroll 1
  for (int i = tid0 * 4; i < 4194304; i += stride * 4) {
    const float4v v = *(const float4v*)(w_out + i);
    u16x4 o; o[0] = f2bf(v[0]); o[1] = f2bf(v[1]); o[2] = f2bf(v[2]); o[3] = f2bf(v[3]);
    *(u16x4*)(woutb + i) = o;
  }
#pragma unroll 1
  for (int idx = tid0; idx < 131072; idx += stride) {
    const int t = idx >> 6, j = idx & 63;
    const float inv = powf(10000.0f, -(float)(j & 31) * (1.0f / 32.0f));
    const float ang = (float)t * inv;
    cst[idx] = make_float2(cosf(ang), sinf(ang));
  }
}

// ------------------------------- GEMM 256x256 4-phase dual-B (fastest measured) ------------
// Epilogue (MODE 1, q/k blocks): cst slice for the block's 256 seqs staged into the
// (now-dead) 128KB LDS -> table reads come from LDS, not scattered global (r8's +73MB FETCH).
#define PH_MFMA(MG, NG, BF)                                                      \
  do {                                                                           \
    _Pragma("unroll") for (int i_ = 0; i_ < 4; ++i_)                             \
      _Pragma("unroll") for (int jn_ = 0; jn_ < 2; ++jn_)                        \
        _Pragma("unroll") for (int ks_ = 0; ks_ < 2; ++ks_)                      \
          acc[(MG) * 4 + i_][(NG) * 2 + jn_] =                                   \
              MFMA_BF16(af[i_][ks_], BF[jn_][ks_],                               \
                        acc[(MG) * 4 + i_][(NG) * 2 + jn_]);                     \
  } while (0)

#define LDB_M(bb, ng, BF)                                                        \
  do {                                                                           \
    const char* base_ = (const char*)&LDS[bb][1][ng][0];                         \
    _Pragma("unroll") for (int jn_ = 0; jn_ < 2; ++jn_) {                        \
      const int R_ = jn_ * 64 + wc * 16 + l15;                                   \
      _Pragma("unroll") for (int ks_ = 0; ks_ < 2; ++ks_)                        \
        BF[jn_][ks_] = *(const bf16x8*)(base_ + R_ * 128 +                       \
                                        ((ks_ * 64 + l4 * 16) ^ ((R_ & 7) << 4)));\
    }                                                                            \
  } while (0)

template <int MODE>
__global__ __launch_bounds__(512, 2) void gemm_bt8(const u16* __restrict__ A,
                                                   const u16* __restrict__ B,
                                                   void* __restrict__ Cv, int M, int N, int K,
                                                   int lda, int ldb, int ldc,
                                                   const float2* __restrict__ cst) {
  __shared__ __align__(16) u16 LDS[2][2][2][128 * 64];  // [buf][A=0/B=1][half][128x64]
  const int nbn = N >> 8;
  const int nwg = gridDim.x;                       // divisible by 8 for our shapes
  const int wg = (blockIdx.x & 7) * (nwg >> 3) + (blockIdx.x >> 3);  // XCD swizzle (T1)
  const int bm = wg / nbn, bn = wg % nbn;
  const int tid = threadIdx.x;
  const int w = tid >> 6, l = tid & 63, l15 = l & 15, l4 = l >> 4;
  const int wr = w >> 2, wc = w & 3;               // 2 M-warps x 4 N-warps
  const u16* Abase = A + (size_t)bm * 256 * lda;
  const u16* Bbase = B + (size_t)bn * 256 * ldb;
  const int NT = K >> 6;

  f32x4 acc[8][4] = {};
  bf16x8 af[4][2], bfr0[2][2], bfr1[2][2];

  auto STAGE = [&](int sel, int h, int t) {
    const u16* src = (sel ? Bbase + (size_t)h * 128 * ldb : Abase + (size_t)h * 128 * lda) +
                     t * 64;
    const int ld = sel ? ldb : lda;
    char* dst = (char*)&LDS[t & 1][sel][h][0];
#pragma unroll
    for (int j = 0; j < 2; ++j) {
      const int o = j * 8192 + tid * 16;
      const int r = o >> 7;
      const int cb = (o & 127) ^ ((r & 7) << 4);
      gll16(src + (size_t)r * ld + (cb >> 1), dst + o);
    }
  };
  auto LDA_ = [&](int bb, int mg) {
    const char* base = (const char*)&LDS[bb][0][mg][0];
#pragma unroll
    for (int i = 0; i < 4; ++i) {
      const int R = i * 32 + wr * 16 + l15;
#pragma unroll
      for (int ks = 0; ks < 2; ++ks)
        af[i][ks] = *(const bf16x8*)(base + R * 128 + ((ks * 64 + l4 * 16) ^ ((R & 7) << 4)));
    }
  };

  // prologue: tile0 {A0,B0,A1,B1} + tile1 {B0,B1,A1}; vmcnt(6) completes tile0
  STAGE(0, 0, 0); STAGE(1, 0, 0); STAGE(0, 1, 0); STAGE(1, 1, 0);
  if (NT > 1) { STAGE(1, 0, 1); STAGE(1, 1, 1); STAGE(0, 1, 1); }
  VMCNT(6);
  BARRIER();

  for (int T = 0; T < NT; ++T) {
    const int bb = T & 1;
    LDA_(bb, 0); LDB_M(bb, 0, bfr0);
    if (T + 1 < NT) STAGE(0, 0, T + 1);
    BARRIER();
    SETP(1); PH_MFMA(0, 0, bfr0); SETP(0);
    BARRIER();
    LDB_M(bb, 1, bfr1);
    if (T + 2 < NT) STAGE(1, 0, T + 2);
    BARRIER();
    SETP(1); PH_MFMA(0, 1, bfr1); SETP(0);
    BARRIER();
    LDA_(bb, 1);
    if (T + 2 < NT) STAGE(1, 1, T + 2);
    BARRIER();
    SETP(1); PH_MFMA(1, 1, bfr1); SETP(0);
    BARRIER();
    if (T + 2 < NT) STAGE(0, 1, T + 2);
    BARRIER();
    SETP(1); PH_MFMA(1, 0, bfr0); SETP(0);
    if (T + 2 < NT) { VMCNT(6); } else { VMCNT(0); }
    BARRIER();
  }

  // q/k blocks: stage this block's cst slice (256 seq x 64 = 128KB) into the dead LDS
  float2* Tlds = (float2*)&LDS[0][0][0][0];
  if (MODE == 1 && bn < 16) {                      // block-uniform branch
    const int seq0 = (bm * 256) & 2047;            // 256-aligned
    const float2* src = cst + (size_t)seq0 * 64;
#pragma unroll
    for (int j = 0; j < 32; ++j) Tlds[j * 512 + tid] = src[j * 512 + tid];
    BARRIER();
  }

  // epilogue: C/D layout col = lane&15, row = (lane>>4)*4 + reg (m89-verified)
#pragma unroll
  for (int mf = 0; mf < 8; ++mf) {
    const int mg = mf >> 2, i = mf & 3;
    const int row0 = bm * 256 + mg * 128 + i * 32 + wr * 16 + l4 * 4;
#pragma unroll
    for (int f = 0; f < 4; ++f) {
      const int col = bn * 256 + f * 64 + wc * 16 + l15;
      const f32x4 a = acc[mf][f];
      if (MODE == 0) {
        float* C = (float*)Cv;
#pragma unroll
        for (int r = 0; r < 4; ++r)
          C[(size_t)(row0 + r) * ldc + col] = a[r];
      } else if (bn < 16) {  // q,k region: RoPE in fp32 (table from LDS), split-half cols
        u16* C = (u16*)Cv;
        const int hc = (f * 64 + wc * 16 + l15) & 127;  // head-relative col
        const int jj = hc >> 1;
        const int odd = hc & 1;
        const int co = (col & ~127) + jj + (odd << 6);  // output col
#pragma unroll
        for (int r = 0; r < 4; ++r) {
          const int row = row0 + r;
          const float v = a[r];
          const float p = __shfl_xor(v, 1);             // partner in (2j,2j+1) pair
          const float2 cv = Tlds[(row & 255) * 64 + jj];
          const float res = odd ? (p * cv.y + v * cv.x)  // out[64+j] = x1*s + x2*c
                                : (v * cv.x - p * cv.y); // out[j]    = x1*c - x2*s
          C[(size_t)row * 6144 + co] = f2bf(res);
        }
      } else {               // V region: transposed into qkvb v-cols, u16x4 (4 consec s)
        u16* C = (u16*)Cv;
        const int batch = row0 >> 11;
        const int s0 = row0 & 2047;
        const int vcol = col - 4096;
        u16* vb = C + (size_t)((batch * 16 + (vcol >> 7)) * 128 + (vcol & 127)) * 6144 +
                  4096 + s0;
        union { u32 u[2]; u16x4 v; } pk;
        pk.u[0] = cvtpk(a[0], a[1]);
        pk.u[1] = cvtpk(a[2], a[3]);
        *(u16x4*)vb = pk.v;
      }
    }
  }
}

// ------------------------------- flash attention (8-wave, 32x32, swapped-QK^T) ---------------
// grid(x=bh=64, y=8), qt = 7-y heavy-first. Triple-buffered K/V staging (counted vmcnt(4));
// defer-max (T13, THR=8). launch_bounds(512,2): flash needs ~96 VGPR (r10: (512,4) spilled).
__global__ __launch_bounds__(512, 2) void flash_attn(u16* __restrict__ qkvb) {
  __shared__ __align__(16) char smem[98304];  // K 3buf [3][16KB] | V 3buf [3][16KB]
  const int bh = blockIdx.x;
  const int qt = 7 - blockIdx.y;
  const int b = bh >> 4, h = bh & 15;
  const int tid = threadIdx.x;
  const int w = tid >> 6, l = tid & 63;
  const int l31 = l & 31, hi = l >> 5;

  const int q0 = qt * 256 + w * 32;           // wave's first q row
  const int qg = q0 + l31;                    // this lane's q (S^T column)

  bf16x8 qf[8];
  {
    const u16* Qrow = qkvb + (size_t)(b * 2048 + qg) * 6144 + h * 128 + hi * 8;
#pragma unroll
    for (int d = 0; d < 8; ++d) qf[d] = *(const bf16x8*)(Qrow + d * 16);
  }

  f32x16 ot[4];
#pragma unroll
  for (int dt = 0; dt < 4; ++dt) ot[dt] = 0.f;
  float mrun = -1e30f, lrun = 0.f;

  const int NT = 4 * qt + 4;
  const u16* Kg0 = qkvb + (size_t)b * 2048 * 6144 + 2048 + h * 128;        // + key*6144
  const u16* Vg0 = qkvb + (size_t)bh * 128 * 6144 + 4096;                  // + d*6144 + key

  auto STAGE = [&](int t, int bi) {
    const u16* Kg = Kg0 + (size_t)t * 64 * 6144;
    const u16* Vg = Vg0 + t * 64;
    char* kd = smem + bi * 16384;
    char* vd = smem + 49152 + bi * 16384;
#pragma unroll
    for (int j = 0; j < 2; ++j) {
      const int o = j * 8192 + tid * 16;
      {  // K tile [64][128] u16, 256B rows, 4-bit swizzle
        const int r = o >> 8;
        const int cb = (o & 255) ^ ((r & 15) << 4);
        gll16(Kg + (size_t)r * 6144 + (cb >> 1), kd + o);
      }
      {  // V^T tile [128][64] u16, 128B rows, 3-bit swizzle; global row stride 6144
        const int r = o >> 7;
        const int cb = (o & 127) ^ ((r & 7) << 4);
        gll16(Vg + (size_t)r * 6144 + (cb >> 1), vd + o);
      }
    }
  };

  // prologue: tiles 0,1 into bufs 0,1; vmcnt(4) completes tile 0 (tile 1 in flight)
  STAGE(0, 0);
  if (NT > 1) { STAGE(1, 1); VMCNT(4); } else { VMCNT(0); }
  BARRIER();

  int cur = 0;
  for (int kt = 0; kt < NT; ++kt) {
    const int nxt = (cur == 0) ? 2 : cur - 1;     // (kt+2) % 3
    if (kt + 2 < NT) STAGE(kt + 2, nxt);

    if (kt * 64 <= q0 + 31) {  // wave-uniform: tile has unmasked keys for this wave
      const char* Kb = smem + cur * 16384;
      const char* Vb = smem + 49152 + cur * 16384;

      // ---- S^T[key][q] = K x Q^T ----
      f32x16 sa[2];
      sa[0] = 0.f; sa[1] = 0.f;
#pragma unroll
      for (int ks2 = 0; ks2 < 2; ++ks2) {
        const int R = ks2 * 32 + l31;
#pragma unroll
        for (int d = 0; d < 8; ++d) {
          const bf16x8 kf = *(const bf16x8*)(Kb + R * 256 +
                                             ((d * 32 + hi * 16) ^ ((R & 15) << 4)));
          sa[ks2] = MFMA32(kf, qf[d], sa[ks2]);
        }
      }

      // ---- scale + mask + tile max ----
      const float SCALE = 0.08838834764831845f;
      float tmax = -1e30f;
      if (kt * 64 + 63 > q0) {
#pragma unroll
        for (int ks2 = 0; ks2 < 2; ++ks2)
#pragma unroll
          for (int rg = 0; rg < 16; ++rg) {
            const int key = kt * 64 + ks2 * 32 + (rg & 3) + 8 * (rg >> 2) + 4 * hi;
            float sv = sa[ks2][rg] * SCALE;
            sv = (key > qg) ? -1e30f : sv;
            sa[ks2][rg] = sv;
            tmax = fmaxf(tmax, sv);
          }
      } else {
#pragma unroll
        for (int ks2 = 0; ks2 < 2; ++ks2)
#pragma unroll
          for (int rg = 0; rg < 16; ++rg) {
            const float sv = sa[ks2][rg] * SCALE;
            sa[ks2][rg] = sv;
            tmax = fmaxf(tmax, sv);
          }
      }
      tmax = fmaxf(tmax, __shfl_xor(tmax, 32));

      // ---- online softmax with defer-max (T13, THR=8): P bounded by e^8 ----
      if (!__all(tmax - mrun <= 8.0f)) {
        const float mnew = fmaxf(mrun, tmax);
        const float alpha = __expf(mrun - mnew);
        mrun = mnew;
        lrun *= alpha;
#pragma unroll
        for (int dt = 0; dt < 4; ++dt)
#pragma unroll
          for (int rg = 0; rg < 16; ++rg) ot[dt][rg] *= alpha;
      }
      float rsum = 0.f;
#pragma unroll
      for (int ks2 = 0; ks2 < 2; ++ks2)
#pragma unroll
        for (int rg = 0; rg < 16; ++rg) {
          const float pv = __expf(sa[ks2][rg] - mrun);
          sa[ks2][rg] = pv;
          rsum += pv;
        }
      rsum += __shfl_xor(rsum, 32);
      lrun += rsum;

      // ---- P^T B-fragments: pack bf16 + lane^32 exchange of 4-key quads ----
      bf16x8 pfrag[4];
#pragma unroll
      for (int t = 0; t < 4; ++t) {
        const int ks2 = t >> 1;
        const int gA = 2 * (t & 1);
        const int gB = gA + 1;
        const u32 a0 = cvtpk(sa[ks2][gA * 4 + 0], sa[ks2][gA * 4 + 1]);
        const u32 a1 = cvtpk(sa[ks2][gA * 4 + 2], sa[ks2][gA * 4 + 3]);
        const u32 b0 = cvtpk(sa[ks2][gB * 4 + 0], sa[ks2][gB * 4 + 1]);
        const u32 b1 = cvtpk(sa[ks2][gB * 4 + 2], sa[ks2][gB * 4 + 3]);
        const u32 snd0 = hi ? a0 : b0;
        const u32 snd1 = hi ? a1 : b1;
        const u32 rcv0 = (u32)__shfl_xor((int)snd0, 32);
        const u32 rcv1 = (u32)__shfl_xor((int)snd1, 32);
        union { u32 u[4]; bf16x8 v; } pk;
        pk.u[0] = hi ? rcv0 : a0;
        pk.u[1] = hi ? rcv1 : a1;
        pk.u[2] = hi ? b0 : rcv0;
        pk.u[3] = hi ? b1 : rcv1;
        pfrag[t] = pk.v;
      }

      // ---- O^T[d][q] += V^T x P^T ----
#pragma unroll
      for (int dt = 0; dt < 4; ++dt) {
        const int R = dt * 32 + l31;
#pragma unroll
        for (int t = 0; t < 4; ++t) {
          const bf16x8 vf = *(const bf16x8*)(Vb + R * 128 +
                                             ((t * 32 + hi * 16) ^ ((R & 7) << 4)));
          ot[dt] = MFMA32(vf, pfrag[t], ot[dt]);
        }
      }
    }

    // counted wait: tile kt+1 complete; tile kt+2's 4 loads stay in flight
    if (kt + 2 < NT) { VMCNT(4); } else { VMCNT(0); }
    BARRIER();
    cur = (cur == 2) ? 0 : cur + 1;
  }

  // ---- epilogue: O^T -> LDS (per-wave 8KB, swizzled) -> coalesced global y ----
  const float inv = 1.0f / lrun;
  char* E = smem + w * 8192;  // [32 q][128 d] u16, 256B rows, 4-bit swizzle
#pragma unroll
  for (int dt = 0; dt < 4; ++dt)
#pragma unroll
    for (int rp = 0; rp < 8; ++rp) {
      const int rg = 2 * rp;
      const int d0 = dt * 32 + (rg & 3) + 8 * (rg >> 2) + 4 * hi;
      const u32 pkv = cvtpk(ot[dt][rg] * inv, ot[dt][rg + 1] * inv);
      *(u32*)(E + l31 * 256 + ((d0 * 2) ^ ((l31 & 15) << 4))) = pkv;
    }
#pragma unroll
  for (int p = 0; p < 8; ++p) {
    const int q = p * 4 + (l >> 4);
    const int c = l & 15;
    const bf16x8 vv = *(const bf16x8*)(E + q * 256 + ((c * 16) ^ ((q & 15) << 4)));
    *(bf16x8*)(qkvb + (size_t)(b * 2048 + q0 + q) * 6144 + h * 128 + c * 8) = vv;
  }
}

// ------------------------------- launch -------------------------------
extern "C" void kernel_launch(void* const* d_in, const int* in_sizes, int n_in,
                              void* d_out, int out_size, void* d_ws, size_t ws_size,
                              hipStream_t stream) {
  const float* x     = (const float*)d_in[0];
  // d_in[1] = mask (causal, implemented analytically)
  const float* w_qkv = (const float*)d_in[2];
  const float* w_out = (const float*)d_in[3];
  float* out = (float*)d_out;
  char* ws = (char*)d_ws;

  // Peak workspace: 161 MB
  u16* woutb = (u16*)(ws);                          // [0,8) MB, live till GEMM2
  u16* xb    = (u16*)(ws + ((size_t)8 << 20));      // [8,40)
  u16* wqkvb = (u16*)(ws + ((size_t)40 << 20));     // [40,64)
  u16* qkvb  = (u16*)(ws + ((size_t)64 << 20));     // [64,160); V transposed in v-cols
  float2* cst = (float2*)(ws + ((size_t)160 << 20)); // 1 MB packed cos/sin

  prep_kernel<<<2048, 256, 0, stream>>>(x, w_qkv, w_out, xb, wqkvb, woutb, cst);
  gemm_bt8<1><<<768, 512, 0, stream>>>(xb, wqkvb, qkvb, 8192, 6144, 2048,
                                       2048, 2048, 6144, cst);
  flash_attn<<<dim3(64, 8), 512, 0, stream>>>(qkvb);
  gemm_bt8<0><<<256, 512, 0, stream>>>(qkvb, woutb, out, 8192, 2048, 2048,
                                       6144, 2048, 2048, nullptr);
}